// Round 13
// baseline (66.730 us; speedup 1.0000x reference)
//
#include <hip/hip_runtime.h>

#define N_    2
#define C_    128
#define H_    128
#define W_    128
#define COUT_ 128
#define K_    9
#define HO_   128
#define WO_   128
#define HW_   (H_*W_)

typedef __attribute__((ext_vector_type(8))) short  short8v;
typedef __attribute__((ext_vector_type(4))) float  float4v;
typedef __attribute__((ext_vector_type(2))) float  float2v;
typedef __attribute__((ext_vector_type(4))) unsigned int uint4v;

__device__ __forceinline__ unsigned short f2bf(float f) {
    union { float f; unsigned int u; } v; v.f = f;
    return (unsigned short)((v.u + 0x7FFFu + ((v.u >> 16) & 1u)) >> 16);  // RNE
}
__device__ __forceinline__ float bflo(unsigned int u) {
    union { unsigned int u; float f; } v; v.u = u << 16; return v.f;
}
__device__ __forceinline__ float bfhi(unsigned int u) {
    union { unsigned int u; float f; } v; v.u = u & 0xFFFF0000u; return v.f;
}
__device__ __forceinline__ unsigned int cvt_pk_bf16(float lo, float hi) {
    unsigned int r;
    asm("v_cvt_pk_bf16_f32 %0, %1, %2" : "=v"(r) : "v"(lo), "v"(hi));  // RNE pack
    return r;
}

// ---- one-time prep: weight pack (A-fragment order) + CHW->HWC bf16 --------
__global__ __launch_bounds__(256)
void prep(const float* __restrict__ x, const float* __restrict__ w,
          unsigned short* __restrict__ xT, unsigned short* __restrict__ wb) {
    if (blockIdx.x >= 256) {                       // ---- pack_w part
        const int t = (blockIdx.x - 256) * 256 + threadIdx.x;
        if (t >= 9 * 8 * 4 * 64) return;
        const int l  = t & 63;
        const int ks = (t >> 6) & 3;
        const int mt = (t >> 8) & 7;
        const int kk = t >> 11;
        const int row = mt * 16 + (l & 15);
        const int c0  = ks * 32 + (l >> 4) * 8;
        unsigned short pk[8];
        #pragma unroll
        for (int j = 0; j < 8; ++j)
            pk[j] = f2bf(w[row * (C_ * K_) + (c0 + j) * K_ + kk]);
        *((short8v*)wb + t) = *(short8v*)pk;
        return;
    }
    // ---- xpose part: one n (bid>>7), 128 pixels
    __shared__ unsigned short tile[128][136];
    const int t  = threadIdx.x;
    const int n  = blockIdx.x >> 7;
    const int p0 = (blockIdx.x & 127) * 128;
    #pragma unroll 4
    for (int i = 0; i < 32; ++i) {
        const int q = i * 2 + (t >> 7);
        const int p = t & 127;
        const float v0 = x[((size_t)(n * C_ + 2 * q    )) * HW_ + p0 + p];
        const float v1 = x[((size_t)(n * C_ + 2 * q + 1)) * HW_ + p0 + p];
        const unsigned int u = (unsigned int)f2bf(v0) | ((unsigned int)f2bf(v1) << 16);
        *(unsigned int*)&tile[p][2 * q] = u;
    }
    __syncthreads();
    const int p    = t >> 1;
    const int half = t & 1;
    unsigned short* dst = xT + ((size_t)(n * HW_ + p0 + p) << 7) + half * 64;
    #pragma unroll
    for (int j = 0; j < 8; ++j)
        *(short8v*)(dst + j * 8) = *(short8v*)&tile[p][half * 64 + j * 8];
}

// ---- fused deformable-im2col + MFMA GEMM, BARRIER-FREE WAVES --------------
// 512 blocks x 256 threads. After one metadata phase, each wave is fully
// self-contained: it owns 16 px x ALL 128 couts and builds its MFMA
// B-fragments IN REGISTERS (gather 4 corners x 16B + combine per lane) --
// no cols LDS, no per-tap barriers, no producer/consumer handoff. 36 slots
// (9 taps x 4 k-steps) with one-slot double-buffered lookahead on both the
// gather and A-fragment streams.
__global__ __launch_bounds__(256, 2)
void dcn_mfma(const unsigned short* __restrict__ xT,
              const float* __restrict__ offset,
              const float* __restrict__ mask,
              const unsigned short* __restrict__ wbuf,
              const float* __restrict__ bias,
              float* __restrict__ out)
{
    __shared__ int4   samp_a[K_ * 64];            // 9.2 KB corner row indices
    __shared__ float4 samp_w[K_ * 64];            // 9.2 KB premult weights

    const int tid = threadIdx.x;
    const int lid = (blockIdx.x & 7) * 64 + (blockIdx.x >> 3);  // XCD swizzle
    const int n   = lid >> 8;
    const int ho  = (lid >> 1) & 127;
    const int wo0 = (lid & 1) * 64;

    // ---- metadata for all 9 taps x 64 pixels (once, one barrier) ----------
    for (int e = tid; e < K_ * 64; e += 256) {
        const int kk  = e >> 6;
        const int wol = e & 63;
        const int wo  = wo0 + wol;
        const int iy = kk / 3, ix = kk % 3;
        const int ob = ((n * 2 * K_ + 2 * kk) * HO_ + ho) * WO_ + wo;
        const float offy = offset[ob];
        const float offx = offset[ob + HO_ * WO_];
        const float m    = mask[((n * K_ + kk) * HO_ + ho) * WO_ + wo];
        const float ys = (float)(ho - 1 + iy) + offy;
        const float xs = (float)(wo - 1 + ix) + offx;
        const float y0f = floorf(ys), x0f = floorf(xs);
        const float ly = ys - y0f, lx = xs - x0f;
        const int y0 = (int)y0f, x0 = (int)x0f;
        const int y1 = y0 + 1,  x1 = x0 + 1;
        const float vy0 = (y0 >= 0 && y0 < H_) ? 1.f : 0.f;
        const float vy1 = (y1 >= 0 && y1 < H_) ? 1.f : 0.f;
        const float vx0 = (x0 >= 0 && x0 < W_) ? 1.f : 0.f;
        const float vx1 = (x1 >= 0 && x1 < W_) ? 1.f : 0.f;
        const int y0c = min(max(y0, 0), H_-1), y1c = min(max(y1, 0), H_-1);
        const int x0c = min(max(x0, 0), W_-1), x1c = min(max(x1, 0), W_-1);
        samp_a[e] = make_int4(y0c*W_+x0c, y0c*W_+x1c, y1c*W_+x0c, y1c*W_+x1c);
        samp_w[e] = make_float4((1.f-ly)*(1.f-lx)*m*vy0*vx0,
                                (1.f-ly)*lx      *m*vy0*vx1,
                                ly      *(1.f-lx)*m*vy1*vx0,
                                ly      *lx      *m*vy1*vx1);
    }
    __syncthreads();          // the ONLY block-wide barrier

    const int lane = tid & 63;
    const int wv   = tid >> 6;              // wave 0..3 -> its 16-px tile
    const int px   = wv * 16 + (lane & 15); // this lane's pixel (0..63)
    const int ck   = (lane >> 4) * 16;      // chunk byte offset within 64B ks

    const char* xb = (const char*)xT + (size_t)n * HW_ * 256;
    const short8v* wb = (const short8v*)wbuf;

    float4v acc[8] = {};                    // 128 cout x 16 px per wave

    uint4v  gaA[4], gaB[4];                 // gather corners, double-buffered
    short8v afA[8], afB[8];                 // A-fragments,     double-buffered
    float4  w4A, w4B;

    // slot t = kk*4 + ks
    auto loadslot = [&](int t, uint4v (&ga)[4], short8v (&af)[8], float4& w4) {
        const int kk = t >> 2, ks = t & 3;
        const int4 rows = samp_a[kk * 64 + px];
        w4 = samp_w[kk * 64 + px];
        const int off = ks * 64 + ck;
        ga[0] = *(const uint4v*)(xb + (size_t)rows.x * 256 + off);
        ga[1] = *(const uint4v*)(xb + (size_t)rows.y * 256 + off);
        ga[2] = *(const uint4v*)(xb + (size_t)rows.z * 256 + off);
        ga[3] = *(const uint4v*)(xb + (size_t)rows.w * 256 + off);
        #pragma unroll
        for (int mt = 0; mt < 8; ++mt)
            af[mt] = wb[((kk * 8 + mt) * 4 + ks) * 64 + lane];
    };
    auto consume = [&](const uint4v (&ga)[4], const short8v (&af)[8],
                       const float4& w4) {
        const float2v wx = {w4.x, w4.x};
        const float2v wy = {w4.y, w4.y};
        const float2v wz = {w4.z, w4.z};
        const float2v ww = {w4.w, w4.w};
        union { uint4v u; short8v s; } b;
        #pragma unroll
        for (int j = 0; j < 4; ++j) {
            const unsigned int u00 = ga[0][j], u01 = ga[1][j];
            const unsigned int u10 = ga[2][j], u11 = ga[3][j];
            const float2v f00 = {bflo(u00), bfhi(u00)};
            const float2v f01 = {bflo(u01), bfhi(u01)};
            const float2v f10 = {bflo(u10), bfhi(u10)};
            const float2v f11 = {bflo(u11), bfhi(u11)};
            const float2v v = wx*f00 + wy*f01 + wz*f10 + ww*f11;
            b.u[j] = cvt_pk_bf16(v[0], v[1]);
        }
        #pragma unroll
        for (int mt = 0; mt < 8; ++mt)
            acc[mt] = __builtin_amdgcn_mfma_f32_16x16x32_bf16(af[mt], b.s, acc[mt], 0, 0, 0);
    };

    loadslot(0, gaA, afA, w4A);
    for (int t = 0; t < 36; t += 2) {
        loadslot(t + 1, gaB, afB, w4B);
        consume(gaA, afA, w4A);
        if (t + 2 < 36) loadslot(t + 2, gaA, afA, w4A);
        consume(gaB, afB, w4B);
    }

    // ---- epilogue: D layout col=lane&15 (wo), row=(lane>>4)*4+reg (cout) --
    const int colw  = lane & 15;
    const int rquad = (lane >> 4) * 4;
    const int woe   = wo0 + wv * 16 + colw;
    #pragma unroll
    for (int mt = 0; mt < 8; ++mt) {
        #pragma unroll
        for (int r = 0; r < 4; ++r) {
            const int co = mt * 16 + rquad + r;
            out[((size_t)(n * COUT_ + co) * HO_ + ho) * WO_ + woe] = acc[mt][r] + bias[co];
        }
    }
}

extern "C" void kernel_launch(void* const* d_in, const int* in_sizes, int n_in,
                              void* d_out, int out_size, void* d_ws, size_t ws_size,
                              hipStream_t stream) {
    const float* x      = (const float*)d_in[0];
    const float* offset = (const float*)d_in[1];
    const float* mask   = (const float*)d_in[2];
    const float* weight = (const float*)d_in[3];
    const float* bias   = (const float*)d_in[4];
    float* out = (float*)d_out;

    unsigned short* xT   = (unsigned short*)d_ws;                    // 8,388,608 B
    unsigned short* wbuf = (unsigned short*)((char*)d_ws + 8388608); // +294,912 B

    prep<<<328, 256, 0, stream>>>(x, weight, xT, wbuf);
    dcn_mfma<<<N_ * HO_ * 2, 256, 0, stream>>>(xT, offset, mask, wbuf, bias, out);
}

// Round 16
// 56.203 us; speedup vs baseline: 1.1873x; 1.1873x over previous
//
#include <hip/hip_runtime.h>

#define N_    2
#define C_    128
#define H_    128
#define W_    128
#define COUT_ 128
#define K_    9
#define HO_   128
#define WO_   128
#define HW_   (H_*W_)

typedef __attribute__((ext_vector_type(8))) short  short8v;
typedef __attribute__((ext_vector_type(4))) float  float4v;
typedef __attribute__((ext_vector_type(2))) float  float2v;
typedef __attribute__((ext_vector_type(4))) unsigned int uint4v;

__device__ __forceinline__ unsigned short f2bf(float f) {
    union { float f; unsigned int u; } v; v.f = f;
    return (unsigned short)((v.u + 0x7FFFu + ((v.u >> 16) & 1u)) >> 16);  // RNE
}
__device__ __forceinline__ float bflo(unsigned int u) {
    union { unsigned int u; float f; } v; v.u = u << 16; return v.f;
}
__device__ __forceinline__ float bfhi(unsigned int u) {
    union { unsigned int u; float f; } v; v.u = u & 0xFFFF0000u; return v.f;
}
__device__ __forceinline__ unsigned int cvt_pk_bf16(float lo, float hi) {
    unsigned int r;
    asm("v_cvt_pk_bf16_f32 %0, %1, %2" : "=v"(r) : "v"(lo), "v"(hi));  // RNE pack
    return r;
}

// ---- one-time prep: weight pack (A-fragment order) + CHW->HWC bf16 --------
__global__ __launch_bounds__(256)
void prep(const float* __restrict__ x, const float* __restrict__ w,
          unsigned short* __restrict__ xT, unsigned short* __restrict__ wb) {
    if (blockIdx.x >= 256) {                       // ---- pack_w part
        const int t = (blockIdx.x - 256) * 256 + threadIdx.x;
        if (t >= 9 * 8 * 4 * 64) return;
        const int l  = t & 63;
        const int ks = (t >> 6) & 3;
        const int mt = (t >> 8) & 7;
        const int kk = t >> 11;
        const int row = mt * 16 + (l & 15);
        const int c0  = ks * 32 + (l >> 4) * 8;
        unsigned short pk[8];
        #pragma unroll
        for (int j = 0; j < 8; ++j)
            pk[j] = f2bf(w[row * (C_ * K_) + (c0 + j) * K_ + kk]);
        *((short8v*)wb + t) = *(short8v*)pk;
        return;
    }
    // ---- xpose part: one n (bid>>7), 128 pixels
    __shared__ unsigned short tile[128][136];
    const int t  = threadIdx.x;
    const int n  = blockIdx.x >> 7;
    const int p0 = (blockIdx.x & 127) * 128;
    #pragma unroll 4
    for (int i = 0; i < 32; ++i) {
        const int q = i * 2 + (t >> 7);
        const int p = t & 127;
        const float v0 = x[((size_t)(n * C_ + 2 * q    )) * HW_ + p0 + p];
        const float v1 = x[((size_t)(n * C_ + 2 * q + 1)) * HW_ + p0 + p];
        const unsigned int u = (unsigned int)f2bf(v0) | ((unsigned int)f2bf(v1) << 16);
        *(unsigned int*)&tile[p][2 * q] = u;
    }
    __syncthreads();
    const int p    = t >> 1;
    const int half = t & 1;
    unsigned short* dst = xT + ((size_t)(n * HW_ + p0 + p) << 7) + half * 64;
    #pragma unroll
    for (int j = 0; j < 8; ++j)
        *(short8v*)(dst + j * 8) = *(short8v*)&tile[p][half * 64 + j * 8];
}

// ---- fused deformable-im2col + MFMA GEMM: in-register B + LDS-staged A ----
// 256 blocks x 256 threads; block = full 128-px output row; wave = 32 px x
// 128 couts (two 16-px B-tiles sharing each A-fragment). A-taps (32 KB)
// staged GLOBAL->REG->ds_write_b128 (identity layout) into a 2-buffer --
// replaces R14/R15's global_load_lds (the suspected corruption source).
// A(kk+2) loads issued a full tap early; plain __syncthreads() per tap.
__global__ __launch_bounds__(256, 1)
void dcn_mfma(const unsigned short* __restrict__ xT,
              const float* __restrict__ offset,
              const float* __restrict__ mask,
              const unsigned short* __restrict__ wbuf,
              const float* __restrict__ bias,
              float* __restrict__ out)
{
    __shared__ __align__(16) unsigned short Abuf[2][16384];  // 2 x 32 KB

    const int tid  = threadIdx.x;
    const int lid  = (blockIdx.x & 7) * 32 + (blockIdx.x >> 3);  // XCD swizzle
    const int n    = lid >> 7;
    const int ho   = lid & 127;

    const int lane = tid & 63;
    const int wv   = tid >> 6;                    // wave 0..3 -> px 32*wv..
    const int pxl  = lane & 15;
    const int ck   = (lane >> 4) * 16;            // 16B chunk within 64B ks-block
    const int wo0t = wv * 32 + pxl;               // tile-0 wo
    const int wo1t = wo0t + 16;                   // tile-1 wo

    const char* xb = (const char*)xT + (size_t)n * HW_ * 256;

    // per-lane sampling metadata (registers; no samp LDS)
    auto meta1 = [&](int kk, int wo, int4& rows, float4& w4) {
        const int iy = kk / 3, ix = kk % 3;
        const int ob = ((n * 2 * K_ + 2 * kk) * HO_ + ho) * WO_ + wo;
        const float offy = offset[ob];
        const float offx = offset[ob + HO_ * WO_];
        const float m    = mask[((n * K_ + kk) * HO_ + ho) * WO_ + wo];
        const float ys = (float)(ho - 1 + iy) + offy;
        const float xs = (float)(wo - 1 + ix) + offx;
        const float y0f = floorf(ys), x0f = floorf(xs);
        const float ly = ys - y0f, lx = xs - x0f;
        const int y0 = (int)y0f, x0 = (int)x0f;
        const int y1 = y0 + 1,  x1 = x0 + 1;
        const float vy0 = (y0 >= 0 && y0 < H_) ? 1.f : 0.f;
        const float vy1 = (y1 >= 0 && y1 < H_) ? 1.f : 0.f;
        const float vx0 = (x0 >= 0 && x0 < W_) ? 1.f : 0.f;
        const float vx1 = (x1 >= 0 && x1 < W_) ? 1.f : 0.f;
        const int y0c = min(max(y0, 0), H_-1), y1c = min(max(y1, 0), H_-1);
        const int x0c = min(max(x0, 0), W_-1), x1c = min(max(x1, 0), W_-1);
        rows = make_int4(y0c*W_+x0c, y0c*W_+x1c, y1c*W_+x0c, y1c*W_+x1c);
        w4   = make_float4((1.f-ly)*(1.f-lx)*m*vy0*vx0,
                           (1.f-ly)*lx      *m*vy0*vx1,
                           ly      *(1.f-lx)*m*vy1*vx0,
                           ly      *lx      *m*vy1*vx1);
    };

    // ---- A staging: global -> regs -> ds_write (identity layout) ----------
    short8v arA[8];
    auto loadAreg = [&](int kk) {
        const short8v* src = (const short8v*)wbuf + kk * 2048;
        #pragma unroll
        for (int j = 0; j < 8; ++j) arA[j] = src[j * 256 + tid];
    };
    auto writeA = [&](int buf) {
        short8v* dst = (short8v*)Abuf[buf];
        #pragma unroll
        for (int j = 0; j < 8; ++j) dst[j * 256 + tid] = arA[j];
    };

    auto gather = [&](const int4& rows, int ks, uint4v (&ga)[4]) {
        const int off = ks * 64 + ck;
        ga[0] = *(const uint4v*)(xb + (size_t)rows.x * 256 + off);
        ga[1] = *(const uint4v*)(xb + (size_t)rows.y * 256 + off);
        ga[2] = *(const uint4v*)(xb + (size_t)rows.z * 256 + off);
        ga[3] = *(const uint4v*)(xb + (size_t)rows.w * 256 + off);
    };
    auto combine = [&](const uint4v (&ga)[4], const float4& w4, short8v& b) {
        const float2v wx = {w4.x, w4.x};
        const float2v wy = {w4.y, w4.y};
        const float2v wz = {w4.z, w4.z};
        const float2v ww = {w4.w, w4.w};
        union { uint4v u; short8v s; } bb;
        #pragma unroll
        for (int j = 0; j < 4; ++j) {
            const unsigned int u00 = ga[0][j], u01 = ga[1][j];
            const unsigned int u10 = ga[2][j], u11 = ga[3][j];
            const float2v f00 = {bflo(u00), bfhi(u00)};
            const float2v f01 = {bflo(u01), bfhi(u01)};
            const float2v f10 = {bflo(u10), bfhi(u10)};
            const float2v f11 = {bflo(u11), bfhi(u11)};
            const float2v v = wx*f00 + wy*f01 + wz*f10 + ww*f11;
            bb.u[j] = cvt_pk_bf16(v[0], v[1]);
        }
        b = bb.s;
    };

    float4v acc[2][8] = {};                       // [tile][mt]
    uint4v gaA[2][4], gaB[2][4];                  // slot-parity dbuf per tile
    int4   rowsC[2], rowsN[2];
    float4 w4C[2],  w4N[2];

    // ---- prologue: A(0)->buf0; hold A(1) in regs; slot-0/1 gathers --------
    loadAreg(0);
    writeA(0);
    loadAreg(1);                                  // A(1) held in arA
    meta1(0, wo0t, rowsC[0], w4C[0]);
    meta1(0, wo1t, rowsC[1], w4C[1]);
    gather(rowsC[0], 0, gaA[0]);  gather(rowsC[1], 0, gaA[1]);
    gather(rowsC[0], 1, gaB[0]);  gather(rowsC[1], 1, gaB[1]);
    __syncthreads();

    #pragma unroll
    for (int kk = 0; kk < K_; ++kk) {
        if (kk < K_ - 1) {
            meta1(kk + 1, wo0t, rowsN[0], w4N[0]);
            meta1(kk + 1, wo1t, rowsN[1], w4N[1]);
            writeA((kk + 1) & 1);                 // A(kk+1) regs -> free buffer
        }
        if (kk < K_ - 2) loadAreg(kk + 2);        // issue next A: full-tap cover

        #pragma unroll
        for (int ks = 0; ks < 4; ++ks) {
            const int t = kk * 4 + ks;
            short8v b0, b1;
            if ((t & 1) == 0) { combine(gaA[0], w4C[0], b0); combine(gaA[1], w4C[1], b1); }
            else              { combine(gaB[0], w4C[0], b0); combine(gaB[1], w4C[1], b1); }
            if (t + 2 < 36) {                     // 2-slot gather lookahead
                const int s2  = (t + 2) & 3;
                const bool nx = ((t + 2) >> 2) != kk;
                if ((t & 1) == 0) {
                    gather(nx ? rowsN[0] : rowsC[0], s2, gaA[0]);
                    gather(nx ? rowsN[1] : rowsC[1], s2, gaA[1]);
                } else {
                    gather(nx ? rowsN[0] : rowsC[0], s2, gaB[0]);
                    gather(nx ? rowsN[1] : rowsC[1], s2, gaB[1]);
                }
            }
            #pragma unroll
            for (int mt = 0; mt < 8; ++mt) {      // A from LDS, reused by 2 tiles
                const short8v af = *(const short8v*)&Abuf[kk & 1][((mt * 4 + ks) * 64 + lane) * 8];
                acc[0][mt] = __builtin_amdgcn_mfma_f32_16x16x32_bf16(af, b0, acc[0][mt], 0, 0, 0);
                acc[1][mt] = __builtin_amdgcn_mfma_f32_16x16x32_bf16(af, b1, acc[1][mt], 0, 0, 0);
            }
        }
        if (kk < K_ - 1) {
            __syncthreads();                      // publish ds_writes + drain
            rowsC[0] = rowsN[0]; rowsC[1] = rowsN[1];
            w4C[0]  = w4N[0];   w4C[1]  = w4N[1];
        }
    }

    // ---- epilogue: D layout col=lane&15 (wo), row=(lane>>4)*4+reg (cout) --
    const int colw  = lane & 15;
    const int rquad = (lane >> 4) * 4;
    #pragma unroll
    for (int tile = 0; tile < 2; ++tile) {
        const int woe = wv * 32 + tile * 16 + colw;
        #pragma unroll
        for (int mt = 0; mt < 8; ++mt) {
            #pragma unroll
            for (int r = 0; r < 4; ++r) {
                const int co = mt * 16 + rquad + r;
                out[((size_t)(n * COUT_ + co) * HO_ + ho) * WO_ + woe] = acc[tile][mt][r] + bias[co];
            }
        }
    }
}

extern "C" void kernel_launch(void* const* d_in, const int* in_sizes, int n_in,
                              void* d_out, int out_size, void* d_ws, size_t ws_size,
                              hipStream_t stream) {
    const float* x      = (const float*)d_in[0];
    const float* offset = (const float*)d_in[1];
    const float* mask   = (const float*)d_in[2];
    const float* weight = (const float*)d_in[3];
    const float* bias   = (const float*)d_in[4];
    float* out = (float*)d_out;

    unsigned short* xT   = (unsigned short*)d_ws;                    // 8,388,608 B
    unsigned short* wbuf = (unsigned short*)((char*)d_ws + 8388608); // +294,912 B

    prep<<<328, 256, 0, stream>>>(x, weight, xT, wbuf);
    dcn_mfma<<<N_ * HO_, 256, 0, stream>>>(xT, offset, mask, wbuf, bias, out);
}

// Round 17
// 38.726 us; speedup vs baseline: 1.7231x; 1.4513x over previous
//
#include <hip/hip_runtime.h>

#define N_    2
#define C_    128
#define H_    128
#define W_    128
#define COUT_ 128
#define K_    9
#define HO_   128
#define WO_   128
#define HW_   (H_*W_)

typedef __attribute__((ext_vector_type(8))) short  short8v;
typedef __attribute__((ext_vector_type(4))) float  float4v;
typedef __attribute__((ext_vector_type(2))) float  float2v;
typedef __attribute__((ext_vector_type(4))) unsigned int uint4v;

__device__ __forceinline__ unsigned short f2bf(float f) {
    union { float f; unsigned int u; } v; v.f = f;
    return (unsigned short)((v.u + 0x7FFFu + ((v.u >> 16) & 1u)) >> 16);  // RNE
}
__device__ __forceinline__ float bflo(unsigned int u) {
    union { unsigned int u; float f; } v; v.u = u << 16; return v.f;
}
__device__ __forceinline__ float bfhi(unsigned int u) {
    union { unsigned int u; float f; } v; v.u = u & 0xFFFF0000u; return v.f;
}
__device__ __forceinline__ unsigned int cvt_pk_bf16(float lo, float hi) {
    unsigned int r;
    asm("v_cvt_pk_bf16_f32 %0, %1, %2" : "=v"(r) : "v"(lo), "v"(hi));  // RNE pack
    return r;
}

// ---- one-time prep: weight pack (A-fragment order) + CHW->HWC bf16 --------
// xpose: 512 blocks x 64-px tiles (2 blocks/CU); pack_w: blocks 512..583.
__global__ __launch_bounds__(256)
void prep(const float* __restrict__ x, const float* __restrict__ w,
          unsigned short* __restrict__ xT, unsigned short* __restrict__ wb) {
    if (blockIdx.x >= 512) {                       // ---- pack_w part
        const int t = (blockIdx.x - 512) * 256 + threadIdx.x;
        if (t >= 9 * 8 * 4 * 64) return;
        const int l  = t & 63;
        const int ks = (t >> 6) & 3;
        const int mt = (t >> 8) & 7;
        const int kk = t >> 11;
        const int row = mt * 16 + (l & 15);
        const int c0  = ks * 32 + (l >> 4) * 8;
        unsigned short pk[8];
        #pragma unroll
        for (int j = 0; j < 8; ++j)
            pk[j] = f2bf(w[row * (C_ * K_) + (c0 + j) * K_ + kk]);
        *((short8v*)wb + t) = *(short8v*)pk;
        return;
    }
    // ---- xpose part: one n (bid>>8), 64 pixels
    __shared__ unsigned short tile[64][136];
    const int t  = threadIdx.x;
    const int n  = blockIdx.x >> 8;
    const int p0 = (blockIdx.x & 255) * 64;
    #pragma unroll
    for (int i = 0; i < 16; ++i) {
        const int q = i * 4 + (t >> 6);            // channel pair 0..63
        const int p = t & 63;
        const float v0 = x[((size_t)(n * C_ + 2 * q    )) * HW_ + p0 + p];
        const float v1 = x[((size_t)(n * C_ + 2 * q + 1)) * HW_ + p0 + p];
        const unsigned int u = (unsigned int)f2bf(v0) | ((unsigned int)f2bf(v1) << 16);
        *(unsigned int*)&tile[p][2 * q] = u;
    }
    __syncthreads();
    const int p  = t >> 2;
    const int c4 = t & 3;                          // 64B quarter of channel row
    unsigned short* dst = xT + ((size_t)(n * HW_ + p0 + p) << 7) + c4 * 32;
    #pragma unroll
    for (int j = 0; j < 4; ++j)
        *(short8v*)(dst + j * 8) = *(short8v*)&tile[p][c4 * 32 + j * 8];
}

// ---- fused deformable-im2col + MFMA GEMM, PRODUCER/CONSUMER waves ---------
// 512 blocks x 512 threads (64-px tile). Waves 0-3 = producers (rotating
// per-px-group gather pipeline, R12), waves 4-7 = consumers. NEW vs R12:
// consumers prefetch tap kk+1's A-fragments BEFORE the non-draining barrier
// (only lgkmcnt drained), so the loads land during producer publish.
__global__ __launch_bounds__(512, 4)
void dcn_mfma(const unsigned short* __restrict__ xT,
              const float* __restrict__ offset,
              const float* __restrict__ mask,
              const unsigned short* __restrict__ wbuf,
              const float* __restrict__ bias,
              float* __restrict__ out)
{
    __shared__ unsigned short colsT[2][64 * 128]; // 32 KB double-buffered
    __shared__ int4   samp_a[K_ * 64];            // 9.2 KB
    __shared__ float4 samp_w[K_ * 64];            // 9.2 KB

    const int tid = threadIdx.x;
    const int lid = (blockIdx.x & 7) * 64 + (blockIdx.x >> 3);  // XCD swizzle
    const int n   = lid >> 8;
    const int ho  = (lid >> 1) & 127;
    const int wo0 = (lid & 1) * 64;

    // ---- metadata for all 9 taps x 64 pixels (all threads) ----------------
    for (int e = tid; e < K_ * 64; e += 512) {
        const int kk  = e >> 6;
        const int wol = e & 63;
        const int wo  = wo0 + wol;
        const int iy = kk / 3, ix = kk % 3;
        const int ob = ((n * 2 * K_ + 2 * kk) * HO_ + ho) * WO_ + wo;
        const float offy = offset[ob];
        const float offx = offset[ob + HO_ * WO_];
        const float m    = mask[((n * K_ + kk) * HO_ + ho) * WO_ + wo];
        const float ys = (float)(ho - 1 + iy) + offy;
        const float xs = (float)(wo - 1 + ix) + offx;
        const float y0f = floorf(ys), x0f = floorf(xs);
        const float ly = ys - y0f, lx = xs - x0f;
        const int y0 = (int)y0f, x0 = (int)x0f;
        const int y1 = y0 + 1,  x1 = x0 + 1;
        const float vy0 = (y0 >= 0 && y0 < H_) ? 1.f : 0.f;
        const float vy1 = (y1 >= 0 && y1 < H_) ? 1.f : 0.f;
        const float vx0 = (x0 >= 0 && x0 < W_) ? 1.f : 0.f;
        const float vx1 = (x1 >= 0 && x1 < W_) ? 1.f : 0.f;
        const int y0c = min(max(y0, 0), H_-1), y1c = min(max(y1, 0), H_-1);
        const int x0c = min(max(x0, 0), W_-1), x1c = min(max(x1, 0), W_-1);
        samp_a[e] = make_int4(y0c*W_+x0c, y0c*W_+x1c, y1c*W_+x0c, y1c*W_+x1c);
        samp_w[e] = make_float4((1.f-ly)*(1.f-lx)*m*vy0*vx0,
                                (1.f-ly)*lx      *m*vy0*vx1,
                                ly      *(1.f-lx)*m*vy1*vx0,
                                ly      *lx      *m*vy1*vx1);
    }
    __syncthreads();

    const int lane = tid & 63;
    const int wv   = tid >> 6;
    const int wvu  = __builtin_amdgcn_readfirstlane(wv);  // scalar branch
    const char* xb = (const char*)xT + (size_t)n * HW_ * 256;

    if (wvu < 4) {
        // ===================== PRODUCER waves (identical to R12) ===========
        const int s16 = lane & 15;          // 16B chunk within 256B px row
        const int ph  = lane >> 4;          // px sub-index

        uint4v ga[4][4];                    // [px-group][corner] rotating set
        float4 w4g[4];

        auto issue = [&](int kk, int pg_) {
            const int px = wvu * 16 + pg_ * 4 + ph;
            const int4 rows = samp_a[kk * 64 + px];
            w4g[pg_] = samp_w[kk * 64 + px];
            ga[pg_][0] = *(const uint4v*)(xb + (size_t)rows.x * 256 + s16 * 16);
            ga[pg_][1] = *(const uint4v*)(xb + (size_t)rows.y * 256 + s16 * 16);
            ga[pg_][2] = *(const uint4v*)(xb + (size_t)rows.z * 256 + s16 * 16);
            ga[pg_][3] = *(const uint4v*)(xb + (size_t)rows.w * 256 + s16 * 16);
        };
        auto publish = [&](int kk, int pg_) {
            const float2v wx = {w4g[pg_].x, w4g[pg_].x};
            const float2v wy = {w4g[pg_].y, w4g[pg_].y};
            const float2v wz = {w4g[pg_].z, w4g[pg_].z};
            const float2v ww = {w4g[pg_].w, w4g[pg_].w};
            uint4v res;
            #pragma unroll
            for (int j = 0; j < 4; ++j) {
                const unsigned int u00 = ga[pg_][0][j], u01 = ga[pg_][1][j];
                const unsigned int u10 = ga[pg_][2][j], u11 = ga[pg_][3][j];
                const float2v f00 = {bflo(u00), bfhi(u00)};
                const float2v f01 = {bflo(u01), bfhi(u01)};
                const float2v f10 = {bflo(u10), bfhi(u10)};
                const float2v f11 = {bflo(u11), bfhi(u11)};
                const float2v v = wx*f00 + wy*f01 + wz*f10 + ww*f11;
                res[j] = cvt_pk_bf16(v[0], v[1]);
            }
            const int px = wvu * 16 + pg_ * 4 + ph;
            const int byte = (px * 256 + s16 * 16) ^ ((px & 7) << 4);
            *(uint4v*)((char*)colsT[kk & 1] + byte) = res;
        };

        #pragma unroll
        for (int pg = 0; pg < 4; ++pg) issue(0, pg);
        #pragma unroll
        for (int pg = 0; pg < 4; ++pg) { publish(0, pg); issue(1, pg); }
        asm volatile("s_waitcnt lgkmcnt(0)" ::: "memory");
        __builtin_amdgcn_s_barrier();
        __builtin_amdgcn_sched_barrier(0);

        #pragma unroll
        for (int kk = 0; kk < K_; ++kk) {
            if (kk < K_ - 1) {
                #pragma unroll
                for (int pg = 0; pg < 4; ++pg) {
                    publish(kk + 1, pg);            // regs from interval kk-1
                    if (kk + 2 < K_) issue(kk + 2, pg);
                }
            }
            asm volatile("s_waitcnt lgkmcnt(0)" ::: "memory");
            __builtin_amdgcn_s_barrier();
            __builtin_amdgcn_sched_barrier(0);
        }
    } else {
        // ===================== CONSUMER waves (R12 + af prefetch) ==========
        const int wvc = wvu - 4;            // 0..3
        const int mt0 = wvc * 2;            // 2 cout-tiles of 16 (32 cout)
        const short8v* wb = (const short8v*)wbuf;
        float4v acc[2][4] = {};             // 32 cout x 64 px

        short8v afA0[4], afA1[4], afB0[4], afB1[4];
        // preload af(0) BEFORE the prologue barrier (stays in flight)
        #pragma unroll
        for (int ks = 0; ks < 4; ++ks) {
            afA0[ks] = wb[((0 * 8 + mt0    ) * 4 + ks) * 64 + lane];
            afA1[ks] = wb[((0 * 8 + mt0 + 1) * 4 + ks) * 64 + lane];
        }
        asm volatile("s_waitcnt lgkmcnt(0)" ::: "memory");
        __builtin_amdgcn_s_barrier();       // matches producer prologue
        __builtin_amdgcn_sched_barrier(0);

        #pragma unroll
        for (int kk = 0; kk < K_; ++kk) {
            const short8v* af0 = (kk & 1) ? afB0 : afA0;
            const short8v* af1 = (kk & 1) ? afB1 : afA1;
            short8v*       nf0 = (kk & 1) ? afA0 : afB0;
            short8v*       nf1 = (kk & 1) ? afA1 : afB1;
            const char* cb = (const char*)colsT[kk & 1];
            __builtin_amdgcn_s_setprio(1);
            #pragma unroll
            for (int ks = 0; ks < 4; ++ks) {
                short8v b[4];
                #pragma unroll
                for (int nt = 0; nt < 4; ++nt) {
                    const int row = nt * 16 + (lane & 15);
                    const int byte = (row * 256 + ks * 64 + (lane >> 4) * 16)
                                   ^ ((row & 7) << 4);
                    b[nt] = *(const short8v*)(cb + byte);
                }
                #pragma unroll
                for (int nt = 0; nt < 4; ++nt) {
                    acc[0][nt] = __builtin_amdgcn_mfma_f32_16x16x32_bf16(af0[ks], b[nt], acc[0][nt], 0, 0, 0);
                    acc[1][nt] = __builtin_amdgcn_mfma_f32_16x16x32_bf16(af1[ks], b[nt], acc[1][nt], 0, 0, 0);
                }
            }
            __builtin_amdgcn_s_setprio(0);
            // prefetch next tap's A-fragments: issued BEFORE the barrier,
            // survive it (only lgkmcnt drained), land during producer publish
            if (kk < K_ - 1) {
                #pragma unroll
                for (int ks = 0; ks < 4; ++ks) {
                    nf0[ks] = wb[(((kk + 1) * 8 + mt0    ) * 4 + ks) * 64 + lane];
                    nf1[ks] = wb[(((kk + 1) * 8 + mt0 + 1) * 4 + ks) * 64 + lane];
                }
            }
            asm volatile("s_waitcnt lgkmcnt(0)" ::: "memory");
            __builtin_amdgcn_s_barrier();
            __builtin_amdgcn_sched_barrier(0);
        }

        // ---- epilogue: D layout col=lane&15 (wo), row=(lane>>4)*4+reg -----
        const int colw  = lane & 15;
        const int rquad = (lane >> 4) * 4;
        #pragma unroll
        for (int mi = 0; mi < 2; ++mi) {
            #pragma unroll
            for (int nt = 0; nt < 4; ++nt) {
                const int woe = wo0 + nt * 16 + colw;
                #pragma unroll
                for (int r = 0; r < 4; ++r) {
                    const int co = (mt0 + mi) * 16 + rquad + r;
                    out[((size_t)(n * COUT_ + co) * HO_ + ho) * WO_ + woe] = acc[mi][nt][r] + bias[co];
                }
            }
        }
    }
}

extern "C" void kernel_launch(void* const* d_in, const int* in_sizes, int n_in,
                              void* d_out, int out_size, void* d_ws, size_t ws_size,
                              hipStream_t stream) {
    const float* x      = (const float*)d_in[0];
    const float* offset = (const float*)d_in[1];
    const float* mask   = (const float*)d_in[2];
    const float* weight = (const float*)d_in[3];
    const float* bias   = (const float*)d_in[4];
    float* out = (float*)d_out;

    unsigned short* xT   = (unsigned short*)d_ws;                    // 8,388,608 B
    unsigned short* wbuf = (unsigned short*)((char*)d_ws + 8388608); // +294,912 B

    prep<<<584, 256, 0, stream>>>(x, weight, xT, wbuf);
    dcn_mfma<<<N_ * HO_ * 2, 512, 0, stream>>>(xT, offset, mask, wbuf, bias, out);
}

// Round 18
// 38.218 us; speedup vs baseline: 1.7460x; 1.0133x over previous
//
#include <hip/hip_runtime.h>

#define N_    2
#define C_    128
#define H_    128
#define W_    128
#define COUT_ 128
#define K_    9
#define HO_   128
#define WO_   128
#define HW_   (H_*W_)

typedef __attribute__((ext_vector_type(8))) short  short8v;
typedef __attribute__((ext_vector_type(4))) float  float4v;
typedef __attribute__((ext_vector_type(2))) float  float2v;
typedef __attribute__((ext_vector_type(4))) unsigned int uint4v;

__device__ __forceinline__ unsigned short f2bf(float f) {
    union { float f; unsigned int u; } v; v.f = f;
    return (unsigned short)((v.u + 0x7FFFu + ((v.u >> 16) & 1u)) >> 16);  // RNE
}
__device__ __forceinline__ float bflo(unsigned int u) {
    union { unsigned int u; float f; } v; v.u = u << 16; return v.f;
}
__device__ __forceinline__ float bfhi(unsigned int u) {
    union { unsigned int u; float f; } v; v.u = u & 0xFFFF0000u; return v.f;
}
__device__ __forceinline__ unsigned int cvt_pk_bf16(float lo, float hi) {
    unsigned int r;
    asm("v_cvt_pk_bf16_f32 %0, %1, %2" : "=v"(r) : "v"(lo), "v"(hi));  // RNE pack
    return r;
}

// ---- one-time prep: weight pack (A-fragment order) + CHW->HWC bf16 --------
// xpose: 512 blocks x 64-px tiles (2 blocks/CU); pack_w: blocks 512..583.
__global__ __launch_bounds__(256)
void prep(const float* __restrict__ x, const float* __restrict__ w,
          unsigned short* __restrict__ xT, unsigned short* __restrict__ wb) {
    if (blockIdx.x >= 512) {                       // ---- pack_w part
        const int t = (blockIdx.x - 512) * 256 + threadIdx.x;
        if (t >= 9 * 8 * 4 * 64) return;
        const int l  = t & 63;
        const int ks = (t >> 6) & 3;
        const int mt = (t >> 8) & 7;
        const int kk = t >> 11;
        const int row = mt * 16 + (l & 15);
        const int c0  = ks * 32 + (l >> 4) * 8;
        unsigned short pk[8];
        #pragma unroll
        for (int j = 0; j < 8; ++j)
            pk[j] = f2bf(w[row * (C_ * K_) + (c0 + j) * K_ + kk]);
        *((short8v*)wb + t) = *(short8v*)pk;
        return;
    }
    // ---- xpose part: one n (bid>>8), 64 pixels
    __shared__ unsigned short tile[64][136];
    const int t  = threadIdx.x;
    const int n  = blockIdx.x >> 8;
    const int p0 = (blockIdx.x & 255) * 64;
    #pragma unroll
    for (int i = 0; i < 16; ++i) {
        const int q = i * 4 + (t >> 6);            // channel pair 0..63
        const int p = t & 63;
        const float v0 = x[((size_t)(n * C_ + 2 * q    )) * HW_ + p0 + p];
        const float v1 = x[((size_t)(n * C_ + 2 * q + 1)) * HW_ + p0 + p];
        const unsigned int u = (unsigned int)f2bf(v0) | ((unsigned int)f2bf(v1) << 16);
        *(unsigned int*)&tile[p][2 * q] = u;
    }
    __syncthreads();
    const int p  = t >> 2;
    const int c4 = t & 3;                          // 64B quarter of channel row
    unsigned short* dst = xT + ((size_t)(n * HW_ + p0 + p) << 7) + c4 * 32;
    #pragma unroll
    for (int j = 0; j < 4; ++j)
        *(short8v*)(dst + j * 8) = *(short8v*)&tile[p][c4 * 32 + j * 8];
}

// ---- fused deformable-im2col + MFMA GEMM, PRODUCER/CONSUMER waves ---------
// Exact R12 champion core (37.8 us). 512 blocks x 512 threads (64-px tile).
// Waves 0-3 = producers (rotating per-px-group gather pipeline: publish tap
// k+1 group pg from regs loaded last interval, then issue tap k+2 group pg),
// waves 4-7 = consumers (A-load + LDS-read + MFMA, setprio'd). One
// non-draining barrier (lgkmcnt-only) per tap; cols double-buffered.
__global__ __launch_bounds__(512, 4)
void dcn_mfma(const unsigned short* __restrict__ xT,
              const float* __restrict__ offset,
              const float* __restrict__ mask,
              const unsigned short* __restrict__ wbuf,
              const float* __restrict__ bias,
              float* __restrict__ out)
{
    __shared__ unsigned short colsT[2][64 * 128]; // 32 KB double-buffered
    __shared__ int4   samp_a[K_ * 64];            // 9.2 KB
    __shared__ float4 samp_w[K_ * 64];            // 9.2 KB

    const int tid = threadIdx.x;
    const int lid = (blockIdx.x & 7) * 64 + (blockIdx.x >> 3);  // XCD swizzle
    const int n   = lid >> 8;
    const int ho  = (lid >> 1) & 127;
    const int wo0 = (lid & 1) * 64;

    // ---- metadata for all 9 taps x 64 pixels (all threads) ----------------
    for (int e = tid; e < K_ * 64; e += 512) {
        const int kk  = e >> 6;
        const int wol = e & 63;
        const int wo  = wo0 + wol;
        const int iy = kk / 3, ix = kk % 3;
        const int ob = ((n * 2 * K_ + 2 * kk) * HO_ + ho) * WO_ + wo;
        const float offy = offset[ob];
        const float offx = offset[ob + HO_ * WO_];
        const float m    = mask[((n * K_ + kk) * HO_ + ho) * WO_ + wo];
        const float ys = (float)(ho - 1 + iy) + offy;
        const float xs = (float)(wo - 1 + ix) + offx;
        const float y0f = floorf(ys), x0f = floorf(xs);
        const float ly = ys - y0f, lx = xs - x0f;
        const int y0 = (int)y0f, x0 = (int)x0f;
        const int y1 = y0 + 1,  x1 = x0 + 1;
        const float vy0 = (y0 >= 0 && y0 < H_) ? 1.f : 0.f;
        const float vy1 = (y1 >= 0 && y1 < H_) ? 1.f : 0.f;
        const float vx0 = (x0 >= 0 && x0 < W_) ? 1.f : 0.f;
        const float vx1 = (x1 >= 0 && x1 < W_) ? 1.f : 0.f;
        const int y0c = min(max(y0, 0), H_-1), y1c = min(max(y1, 0), H_-1);
        const int x0c = min(max(x0, 0), W_-1), x1c = min(max(x1, 0), W_-1);
        samp_a[e] = make_int4(y0c*W_+x0c, y0c*W_+x1c, y1c*W_+x0c, y1c*W_+x1c);
        samp_w[e] = make_float4((1.f-ly)*(1.f-lx)*m*vy0*vx0,
                                (1.f-ly)*lx      *m*vy0*vx1,
                                ly      *(1.f-lx)*m*vy1*vx0,
                                ly      *lx      *m*vy1*vx1);
    }
    __syncthreads();

    const int lane = tid & 63;
    const int wv   = tid >> 6;
    const int wvu  = __builtin_amdgcn_readfirstlane(wv);  // scalar branch
    const char* xb = (const char*)xT + (size_t)n * HW_ * 256;

    if (wvu < 4) {
        // ===================== PRODUCER waves ==============================
        const int s16 = lane & 15;          // 16B chunk within 256B px row
        const int ph  = lane >> 4;          // px sub-index

        uint4v ga[4][4];                    // [px-group][corner] rotating set
        float4 w4g[4];

        auto issue = [&](int kk, int pg_) {
            const int px = wvu * 16 + pg_ * 4 + ph;
            const int4 rows = samp_a[kk * 64 + px];
            w4g[pg_] = samp_w[kk * 64 + px];
            ga[pg_][0] = *(const uint4v*)(xb + (size_t)rows.x * 256 + s16 * 16);
            ga[pg_][1] = *(const uint4v*)(xb + (size_t)rows.y * 256 + s16 * 16);
            ga[pg_][2] = *(const uint4v*)(xb + (size_t)rows.z * 256 + s16 * 16);
            ga[pg_][3] = *(const uint4v*)(xb + (size_t)rows.w * 256 + s16 * 16);
        };
        auto publish = [&](int kk, int pg_) {
            const float2v wx = {w4g[pg_].x, w4g[pg_].x};
            const float2v wy = {w4g[pg_].y, w4g[pg_].y};
            const float2v wz = {w4g[pg_].z, w4g[pg_].z};
            const float2v ww = {w4g[pg_].w, w4g[pg_].w};
            uint4v res;
            #pragma unroll
            for (int j = 0; j < 4; ++j) {
                const unsigned int u00 = ga[pg_][0][j], u01 = ga[pg_][1][j];
                const unsigned int u10 = ga[pg_][2][j], u11 = ga[pg_][3][j];
                const float2v f00 = {bflo(u00), bfhi(u00)};
                const float2v f01 = {bflo(u01), bfhi(u01)};
                const float2v f10 = {bflo(u10), bfhi(u10)};
                const float2v f11 = {bflo(u11), bfhi(u11)};
                const float2v v = wx*f00 + wy*f01 + wz*f10 + ww*f11;
                res[j] = cvt_pk_bf16(v[0], v[1]);
            }
            const int px = wvu * 16 + pg_ * 4 + ph;
            const int byte = (px * 256 + s16 * 16) ^ ((px & 7) << 4);
            *(uint4v*)((char*)colsT[kk & 1] + byte) = res;
        };

        // prologue: tap0 load+publish, then issue tap1
        #pragma unroll
        for (int pg = 0; pg < 4; ++pg) issue(0, pg);
        #pragma unroll
        for (int pg = 0; pg < 4; ++pg) { publish(0, pg); issue(1, pg); }
        asm volatile("s_waitcnt lgkmcnt(0)" ::: "memory");
        __builtin_amdgcn_s_barrier();
        __builtin_amdgcn_sched_barrier(0);

        #pragma unroll
        for (int kk = 0; kk < K_; ++kk) {
            if (kk < K_ - 1) {
                #pragma unroll
                for (int pg = 0; pg < 4; ++pg) {
                    publish(kk + 1, pg);            // regs from interval kk-1
                    if (kk + 2 < K_) issue(kk + 2, pg);  // ~full-interval cover
                }
            }
            asm volatile("s_waitcnt lgkmcnt(0)" ::: "memory");
            __builtin_amdgcn_s_barrier();
            __builtin_amdgcn_sched_barrier(0);
        }
    } else {
        // ===================== CONSUMER waves ==============================
        const int wvc = wvu - 4;            // 0..3
        const int mt0 = wvc * 2;            // 2 cout-tiles of 16 (32 cout)
        const short8v* wb = (const short8v*)wbuf;
        float4v acc[2][4] = {};             // 32 cout x 64 px

        asm volatile("s_waitcnt lgkmcnt(0)" ::: "memory");
        __builtin_amdgcn_s_barrier();       // matches producer prologue
        __builtin_amdgcn_sched_barrier(0);

        for (int kk = 0; kk < K_; ++kk) {
            short8v af0[4], af1[4];
            #pragma unroll
            for (int ks = 0; ks < 4; ++ks) {
                af0[ks] = wb[((kk * 8 + mt0    ) * 4 + ks) * 64 + lane];
                af1[ks] = wb[((kk * 8 + mt0 + 1) * 4 + ks) * 64 + lane];
            }
            const char* cb = (const char*)colsT[kk & 1];
            __builtin_amdgcn_s_setprio(1);
            #pragma unroll
            for (int ks = 0; ks < 4; ++ks) {
                short8v b[4];
                #pragma unroll
                for (int nt = 0; nt < 4; ++nt) {
                    const int row = nt * 16 + (lane & 15);
                    const int byte = (row * 256 + ks * 64 + (lane >> 4) * 16)
                                   ^ ((row & 7) << 4);
                    b[nt] = *(const short8v*)(cb + byte);
                }
                #pragma unroll
                for (int nt = 0; nt < 4; ++nt) {
                    acc[0][nt] = __builtin_amdgcn_mfma_f32_16x16x32_bf16(af0[ks], b[nt], acc[0][nt], 0, 0, 0);
                    acc[1][nt] = __builtin_amdgcn_mfma_f32_16x16x32_bf16(af1[ks], b[nt], acc[1][nt], 0, 0, 0);
                }
            }
            __builtin_amdgcn_s_setprio(0);
            asm volatile("s_waitcnt lgkmcnt(0)" ::: "memory");
            __builtin_amdgcn_s_barrier();
            __builtin_amdgcn_sched_barrier(0);
        }

        // ---- epilogue: D layout col=lane&15 (wo), row=(lane>>4)*4+reg -----
        const int colw  = lane & 15;
        const int rquad = (lane >> 4) * 4;
        #pragma unroll
        for (int mi = 0; mi < 2; ++mi) {
            #pragma unroll
            for (int nt = 0; nt < 4; ++nt) {
                const int woe = wo0 + nt * 16 + colw;
                #pragma unroll
                for (int r = 0; r < 4; ++r) {
                    const int co = (mt0 + mi) * 16 + rquad + r;
                    out[((size_t)(n * COUT_ + co) * HO_ + ho) * WO_ + woe] = acc[mi][nt][r] + bias[co];
                }
            }
        }
    }
}

extern "C" void kernel_launch(void* const* d_in, const int* in_sizes, int n_in,
                              void* d_out, int out_size, void* d_ws, size_t ws_size,
                              hipStream_t stream) {
    const float* x      = (const float*)d_in[0];
    const float* offset = (const float*)d_in[1];
    const float* mask   = (const float*)d_in[2];
    const float* weight = (const float*)d_in[3];
    const float* bias   = (const float*)d_in[4];
    float* out = (float*)d_out;

    unsigned short* xT   = (unsigned short*)d_ws;                    // 8,388,608 B
    unsigned short* wbuf = (unsigned short*)((char*)d_ws + 8388608); // +294,912 B

    prep<<<584, 256, 0, stream>>>(x, weight, xT, wbuf);
    dcn_mfma<<<N_ * HO_ * 2, 512, 0, stream>>>(xT, offset, mask, wbuf, bias, out);
}